// Round 2
// baseline (237.080 us; speedup 1.0000x reference)
//
#include <hip/hip_runtime.h>
#include <hip/hip_bf16.h>

typedef __attribute__((ext_vector_type(8))) short short8;
typedef __attribute__((ext_vector_type(4))) float f32x4;

#define D 512
#define BM 128
#define BN 128
#define BK 64

typedef const __attribute__((address_space(1))) void gvoid;
typedef __attribute__((address_space(3))) void lvoid;

__device__ inline unsigned pack2f(float lo, float hi) {
    __hip_bfloat162 v = __float22bfloat162_rn(make_float2(lo, hi));
    union { __hip_bfloat162 h; unsigned u; } cv;
    cv.h = v;
    return cv.u;
}

__device__ inline int4 pack8f(const float4& v0, const float4& v1, float sc) {
    int4 r;
    r.x = (int)pack2f(v0.x * sc, v0.y * sc);
    r.y = (int)pack2f(v0.z * sc, v0.w * sc);
    r.z = (int)pack2f(v1.x * sc, v1.y * sc);
    r.w = (int)pack2f(v1.z * sc, v1.w * sc);
    return r;
}

// Kernel 1: per-pair norms, fp32 diagonal cos, zero sumexp, optional bf16 cache.
__global__ __launch_bounds__(256) void norm_kernel(
    const float* __restrict__ x,
    float* __restrict__ pinv, float* __restrict__ ainv,
    float* __restrict__ diag, float* __restrict__ sumexp,
    __hip_bfloat16* __restrict__ Pn, __hip_bfloat16* __restrict__ An, int cached)
{
    const int i = blockIdx.x, t = threadIdx.x;
    const float2* ap = (const float2*)(x + (size_t)(2 * i) * D);
    const float2* pp = (const float2*)(x + (size_t)(2 * i + 1) * D);
    float2 a = ap[t], p = pp[t];
    float ssa = a.x * a.x + a.y * a.y;
    float ssp = p.x * p.x + p.y * p.y;
    float dt  = p.x * a.x + p.y * a.y;
#pragma unroll
    for (int m = 1; m < 64; m <<= 1) {
        ssa += __shfl_xor(ssa, m);
        ssp += __shfl_xor(ssp, m);
        dt  += __shfl_xor(dt, m);
    }
    __shared__ float red[3][4];
    if ((t & 63) == 0) { int wv = t >> 6; red[0][wv] = ssa; red[1][wv] = ssp; red[2][wv] = dt; }
    __syncthreads();
    ssa = red[0][0] + red[0][1] + red[0][2] + red[0][3];
    ssp = red[1][0] + red[1][1] + red[1][2] + red[1][3];
    dt  = red[2][0] + red[2][1] + red[2][2] + red[2][3];
    float an = sqrtf(ssa), pn = sqrtf(ssp);
    float ia = 1.0f / fmaxf(an, 1e-30f);
    float ip = 1.0f / fmaxf(pn, 1e-30f);
    if (t == 0) {
        ainv[i] = ia;
        pinv[i] = ip;
        diag[i] = dt / fmaxf(pn * an, 1e-8f);
        sumexp[i] = 0.0f;
    }
    if (cached) {
        ((__hip_bfloat162*)(Pn + (size_t)i * D))[t] = __float22bfloat162_rn(make_float2(p.x * ip, p.y * ip));
        ((__hip_bfloat162*)(An + (size_t)i * D))[t] = __float22bfloat162_rn(make_float2(a.x * ia, a.y * ia));
    }
}

// Kernel 2 (cached path): m97-structure fused GEMM + per-row sum of exp(w*cos - |w|).
// 128x128 tile, BK=64, 4 waves (2x2), each wave 64x64 via 4x4 mfma_16x16x32_bf16.
// global_load_lds width=16, linear LDS dest + inverse-swizzled source + swizzled ds_read.
__global__ __launch_bounds__(256) void gemm_lse_128(
    const __hip_bfloat16* __restrict__ Pn, const __hip_bfloat16* __restrict__ An,
    const float* __restrict__ wp, float* __restrict__ sumexp)
{
    __shared__ __align__(16) unsigned char lds[32768];
    unsigned char* As = lds;            // 128 rows x 128 B (64 bf16), swizzled slots
    unsigned char* Bs = lds + 16384;

    const int t = threadIdx.x;
    const int lane = t & 63, w = t >> 6;
    const int wr = w >> 1, wc = w & 1;
    const int l15 = lane & 15, lhi = lane >> 4;
    const int brow = blockIdx.y * BM;
    const int bcol = blockIdx.x * BN;

    const float wv = *wp;
    const float s = fabsf(wv);

    f32x4 acc[4][4];
#pragma unroll
    for (int mi = 0; mi < 4; ++mi)
#pragma unroll
        for (int ni = 0; ni < 4; ++ni)
#pragma unroll
            for (int j = 0; j < 4; ++j) acc[mi][ni][j] = 0.0f;

    const int o0 = t * 16;

    for (int kt = 0; kt < D / BK; ++kt) {
        // ---- stage A,B tiles: 16 KB each via global_load_lds width=16 ----
#pragma unroll
        for (int i = 0; i < 4; ++i) {
            int o = i * 4096 + o0;                       // linear LDS byte offset
            int row = o >> 7;                            // 0..127
            int sslot = ((o >> 4) & 7) ^ (row & 7);      // inverse-swizzled source slot
            const __hip_bfloat16* ga = Pn + (size_t)(brow + row) * D + kt * BK + sslot * 8;
            const __hip_bfloat16* gb = An + (size_t)(bcol + row) * D + kt * BK + sslot * 8;
            __builtin_amdgcn_global_load_lds((gvoid*)ga, (lvoid*)(As + o), 16, 0, 0);
            __builtin_amdgcn_global_load_lds((gvoid*)gb, (lvoid*)(Bs + o), 16, 0, 0);
        }
        __syncthreads();   // compiler drains vmcnt before s_barrier

        // ---- compute: 2 k-subtiles x 16 MFMA ----
#pragma unroll
        for (int ks = 0; ks < 2; ++ks) {
            short8 a[4], b[4];
            const int kb = ks * 64 + lhi * 16;           // byte offset of 16B slot
#pragma unroll
            for (int mi = 0; mi < 4; ++mi) {
                int r = wr * 64 + mi * 16 + l15;
                a[mi] = *(const short8*)(As + r * 128 + (kb ^ ((r & 7) << 4)));
            }
#pragma unroll
            for (int ni = 0; ni < 4; ++ni) {
                int c = wc * 64 + ni * 16 + l15;
                b[ni] = *(const short8*)(Bs + c * 128 + (kb ^ ((c & 7) << 4)));
            }
#pragma unroll
            for (int mi = 0; mi < 4; ++mi)
#pragma unroll
                for (int ni = 0; ni < 4; ++ni)
                    acc[mi][ni] = __builtin_amdgcn_mfma_f32_16x16x32_bf16(a[mi], b[ni], acc[mi][ni], 0, 0, 0);
        }
        __syncthreads();   // LDS reuse protection before next stage
    }

    // ---- epilogue: exp + row-sum + one atomic per row ----
#pragma unroll
    for (int mi = 0; mi < 4; ++mi) {
#pragma unroll
        for (int j = 0; j < 4; ++j) {
            float v = 0.0f;
#pragma unroll
            for (int ni = 0; ni < 4; ++ni)
                v += __expf(acc[mi][ni][j] * wv - s);
            v += __shfl_xor(v, 1);
            v += __shfl_xor(v, 2);
            v += __shfl_xor(v, 4);
            v += __shfl_xor(v, 8);
            if (l15 == 0) {
                int row = brow + wr * 64 + mi * 16 + lhi * 4 + j;
                atomicAdd(&sumexp[row], v);
            }
        }
    }
}

// Fallback (uncached ws): round-1 proven kernel, normalizes on the fly.
__global__ __launch_bounds__(256, 2) void gemm_lse_small(
    const float* __restrict__ x,
    const float* __restrict__ pinv, const float* __restrict__ ainv,
    const float* __restrict__ wp, float* __restrict__ sumexp, int N)
{
    __shared__ __align__(16) unsigned char lds[81920];
    unsigned char* As = lds;
    unsigned char* Bs = lds + 65536;

    const int t = threadIdx.x;
    const int rb = blockIdx.y, cs = blockIdx.x;
    const int lane = t & 63, w = t >> 6;
    const int wr = w >> 1, wc = w & 1;
    const int l15 = lane & 15, lhi = lane >> 4;

    const int colsPer = N >> 3;
    const int CT = colsPer / 64;
    const int Q = CT * (D / 64);

    {
        int r = t >> 2;
        int kq = (t & 3) << 7;
        int grow = rb * 64 + r;
        const float4* src = (const float4*)(x + (size_t)(2 * grow + 1) * D);
        float sc = pinv[grow];
#pragma unroll
        for (int i2 = 0; i2 < 16; ++i2) {
            int k0 = kq + i2 * 8;
            float4 v0 = src[k0 >> 2], v1 = src[(k0 >> 2) + 1];
            *(int4*)(As + r * 1024 + ((k0 * 2) ^ ((r & 7) << 4))) = pack8f(v0, v1, sc);
        }
    }

    const int cl = t >> 2;
    const int kq = (t & 3) << 4;

    auto loadB = [&](int q, int4& oa, int4& ob) {
        int ct = q >> 3, kc = q & 7;
        int c = cs * colsPer + ct * 64 + cl;
        int k = kc * 64 + kq;
        const float4* src = (const float4*)(x + (size_t)(2 * c) * D + k);
        float sc = ainv[c];
        float4 v0 = src[0], v1 = src[1], v2 = src[2], v3 = src[3];
        oa = pack8f(v0, v1, sc);
        ob = pack8f(v2, v3, sc);
    };
    auto writeB = [&](int buf, const int4& oa, const int4& ob) {
        unsigned char* bb = Bs + buf * 8192 + cl * 128;
        int kb0 = kq * 2;
        *(int4*)(bb + (kb0 ^ ((cl & 7) << 4))) = oa;
        *(int4*)(bb + ((kb0 + 16) ^ ((cl & 7) << 4))) = ob;
    };

    const float wv = *wp;
    const float s = fabsf(wv);

    int4 ba, bb2;
    loadB(0, ba, bb2);
    __syncthreads();
    writeB(0, ba, bb2);
    __syncthreads();

    f32x4 acc[2][2];
    float rs[2][4];
#pragma unroll
    for (int mi = 0; mi < 2; ++mi) {
#pragma unroll
        for (int j = 0; j < 4; ++j) rs[mi][j] = 0.0f;
#pragma unroll
        for (int ni = 0; ni < 2; ++ni)
#pragma unroll
            for (int j = 0; j < 4; ++j) acc[mi][ni][j] = 0.0f;
    }

    for (int q = 0; q < Q; ++q) {
        const int kc = q & 7;
        const bool more = (q + 1 < Q);
        if (more) loadB(q + 1, ba, bb2);
        const unsigned char* Bp = Bs + (q & 1) * 8192;
#pragma unroll
        for (int ks = 0; ks < 2; ++ks) {
            int ka = kc * 64 + ks * 32 + lhi * 8;
            int ra0 = wr * 32 + l15, ra1 = ra0 + 16;
            short8 a0 = *(const short8*)(As + ra0 * 1024 + ((ka * 2) ^ ((ra0 & 7) << 4)));
            short8 a1 = *(const short8*)(As + ra1 * 1024 + ((ka * 2) ^ ((ra1 & 7) << 4)));
            int kb = ks * 32 + lhi * 8;
            int c0 = wc * 32 + l15, c1 = c0 + 16;
            short8 b0 = *(const short8*)(Bp + c0 * 128 + ((kb * 2) ^ ((c0 & 7) << 4)));
            short8 b1 = *(const short8*)(Bp + c1 * 128 + ((kb * 2) ^ ((c1 & 7) << 4)));
            acc[0][0] = __builtin_amdgcn_mfma_f32_16x16x32_bf16(a0, b0, acc[0][0], 0, 0, 0);
            acc[0][1] = __builtin_amdgcn_mfma_f32_16x16x32_bf16(a0, b1, acc[0][1], 0, 0, 0);
            acc[1][0] = __builtin_amdgcn_mfma_f32_16x16x32_bf16(a1, b0, acc[1][0], 0, 0, 0);
            acc[1][1] = __builtin_amdgcn_mfma_f32_16x16x32_bf16(a1, b1, acc[1][1], 0, 0, 0);
        }
        if (kc == 7) {
#pragma unroll
            for (int mi = 0; mi < 2; ++mi)
#pragma unroll
                for (int ni = 0; ni < 2; ++ni)
#pragma unroll
                    for (int j = 0; j < 4; ++j) {
                        rs[mi][j] += __expf(acc[mi][ni][j] * wv - s);
                        acc[mi][ni][j] = 0.0f;
                    }
        }
        if (more) {
            __syncthreads();
            writeB((q + 1) & 1, ba, bb2);
            __syncthreads();
        }
    }

#pragma unroll
    for (int mi = 0; mi < 2; ++mi)
#pragma unroll
        for (int j = 0; j < 4; ++j) {
            float v = rs[mi][j];
            v += __shfl_xor(v, 1);
            v += __shfl_xor(v, 2);
            v += __shfl_xor(v, 4);
            v += __shfl_xor(v, 8);
            if (l15 == 0) {
                int row = rb * 64 + wr * 32 + mi * 16 + lhi * 4 + j;
                atomicAdd(&sumexp[row], v);
            }
        }
}

// Kernel 3: loss_i = |w| + log(sumexp_i) - w*diag_i ; out = mean(loss)
__global__ __launch_bounds__(1024) void finalize_kernel(
    const float* __restrict__ sumexp, const float* __restrict__ diag,
    const float* __restrict__ wp, float* __restrict__ out, int N)
{
    const int t = threadIdx.x;
    const float w = *wp;
    const float s = fabsf(w);
    float acc = 0.0f;
    for (int i = t; i < N; i += 1024)
        acc += s + logf(sumexp[i]) - w * diag[i];
#pragma unroll
    for (int m = 1; m < 64; m <<= 1) acc += __shfl_xor(acc, m);
    __shared__ float red[16];
    if ((t & 63) == 0) red[t >> 6] = acc;
    __syncthreads();
    if (t == 0) {
        float v = 0.0f;
#pragma unroll
        for (int i = 0; i < 16; ++i) v += red[i];
        out[0] = v / (float)N;
    }
}

extern "C" void kernel_launch(void* const* d_in, const int* in_sizes, int n_in,
                              void* d_out, int out_size, void* d_ws, size_t ws_size,
                              hipStream_t stream) {
    const float* x  = (const float*)d_in[0];
    const float* wp = (const float*)d_in[1];
    // b (d_in[2]) cancels in log_softmax diagonal term.

    const int N = in_sizes[0] / (2 * D);     // 8192

    char* ws = (char*)d_ws;
    size_t nf = (size_t)N * 4;
    float* pinv   = (float*)(ws);
    float* ainv   = (float*)(ws + nf);
    float* diag   = (float*)(ws + 2 * nf);
    float* sumexp = (float*)(ws + 3 * nf);
    size_t base = (4 * nf + 255) & ~(size_t)255;
    __hip_bfloat16* Pn = (__hip_bfloat16*)(ws + base);
    __hip_bfloat16* An = (__hip_bfloat16*)(ws + base + (size_t)N * D * 2);
    const bool cached = ws_size >= base + (size_t)N * D * 4;

    norm_kernel<<<N, 256, 0, stream>>>(x, pinv, ainv, diag, sumexp, Pn, An, cached ? 1 : 0);

    if (cached) {
        dim3 grid(N / BN, N / BM);
        gemm_lse_128<<<grid, 256, 0, stream>>>(Pn, An, wp, sumexp);
    } else {
        dim3 grid(8, N / 64);
        gemm_lse_small<<<grid, 256, 0, stream>>>(x, pinv, ainv, wp, sumexp, N);
    }

    finalize_kernel<<<1, 1024, 0, stream>>>(sumexp, diag, wp, (float*)d_out, N);
}

// Round 5
// 223.721 us; speedup vs baseline: 1.0597x; 1.0597x over previous
//
#include <hip/hip_runtime.h>
#include <hip/hip_bf16.h>

typedef __attribute__((ext_vector_type(8))) short short8;
typedef __attribute__((ext_vector_type(4))) float f32x4;

#define D 512
#define NT 8            // K-tiles = D/64

typedef const __attribute__((address_space(1))) void gvoid;
typedef __attribute__((address_space(3))) void lvoid;

__device__ inline unsigned pack2f(float lo, float hi) {
    __hip_bfloat162 v = __float22bfloat162_rn(make_float2(lo, hi));
    union { __hip_bfloat162 h; unsigned u; } cv;
    cv.h = v;
    return cv.u;
}

__device__ inline int4 pack8f(const float4& v0, const float4& v1, float sc) {
    int4 r;
    r.x = (int)pack2f(v0.x * sc, v0.y * sc);
    r.y = (int)pack2f(v0.z * sc, v0.w * sc);
    r.z = (int)pack2f(v1.x * sc, v1.y * sc);
    r.w = (int)pack2f(v1.z * sc, v1.w * sc);
    return r;
}

// Kernel 1: one wave per pair. Norms, fp32 diag cos, zero sumexp, bf16 normalized cache.
__global__ __launch_bounds__(512) void norm_kernel(
    const float* __restrict__ x,
    float* __restrict__ diag, float* __restrict__ sumexp,
    __hip_bfloat16* __restrict__ Pn, __hip_bfloat16* __restrict__ An)
{
    const int t = threadIdx.x;
    const int i = blockIdx.x * 8 + (t >> 6);
    const int lane = t & 63;
    const float4* ap = (const float4*)(x + (size_t)(2 * i) * D);
    const float4* pp = (const float4*)(x + (size_t)(2 * i + 1) * D);
    float4 a0 = ap[lane * 2], a1 = ap[lane * 2 + 1];
    float4 p0 = pp[lane * 2], p1 = pp[lane * 2 + 1];
    float ssa = a0.x*a0.x + a0.y*a0.y + a0.z*a0.z + a0.w*a0.w
              + a1.x*a1.x + a1.y*a1.y + a1.z*a1.z + a1.w*a1.w;
    float ssp = p0.x*p0.x + p0.y*p0.y + p0.z*p0.z + p0.w*p0.w
              + p1.x*p1.x + p1.y*p1.y + p1.z*p1.z + p1.w*p1.w;
    float dt  = p0.x*a0.x + p0.y*a0.y + p0.z*a0.z + p0.w*a0.w
              + p1.x*a1.x + p1.y*a1.y + p1.z*a1.z + p1.w*a1.w;
#pragma unroll
    for (int m = 1; m < 64; m <<= 1) {
        ssa += __shfl_xor(ssa, m);
        ssp += __shfl_xor(ssp, m);
        dt  += __shfl_xor(dt, m);
    }
    float an = sqrtf(ssa), pn = sqrtf(ssp);
    float ia = 1.0f / fmaxf(an, 1e-30f);
    float ip = 1.0f / fmaxf(pn, 1e-30f);
    if (lane == 0) {
        diag[i] = dt / fmaxf(pn * an, 1e-8f);
        sumexp[i] = 0.0f;
    }
    int4 wp_, wa_;
    wp_ = pack8f(make_float4(p0.x,p0.y,p0.z,p0.w), make_float4(p1.x,p1.y,p1.z,p1.w), ip);
    wa_ = pack8f(make_float4(a0.x,a0.y,a0.z,a0.w), make_float4(a1.x,a1.y,a1.z,a1.w), ia);
    ((int4*)(Pn + (size_t)i * D))[lane] = wp_;
    ((int4*)(An + (size_t)i * D))[lane] = wa_;
}

// Kernel 2: 256x256 tile, BK=64, counted-vmcnt pipelined, fused LSE epilogue.
// 8 waves (2M x 4N), each 128x64 output via 8x4 16x16x32 MFMA frags.
// LDS 128 KB: [A|B] x [dbuf 2] x [half 2] x (128 rows x 64 bf16, XOR-swizzled slots).
__global__ __launch_bounds__(512, 2) void gemm_lse_256(
    const __hip_bfloat16* __restrict__ Pn, const __hip_bfloat16* __restrict__ An,
    const float* __restrict__ wp, float* __restrict__ sumexp, int nbx)
{
    __shared__ __align__(16) unsigned char lds[131072];

    const int t = threadIdx.x;
    const int lane = t & 63, w = t >> 6;
    const int wm = w >> 2, wn = w & 3;
    const int l15 = lane & 15, lhi = lane >> 4;
    const int swz = (l15 & 7) << 4;
    const int kb0 = lhi * 16, kb1 = 64 + lhi * 16;

    // bijective XCD-chunked swizzle (nwg = nbx*nbx, divisible by 8)
    const int nwg = nbx * nbx;
    const int cpx = nwg >> 3;
    const int bid = blockIdx.x;
    const int wgid = (bid & 7) * cpx + (bid >> 3);
    const int brow = (wgid / nbx) * 256;
    const int bcol = (wgid % nbx) * 256;

    const float wv = *wp;
    const float s = fabsf(wv);

    // per-thread staging geometry: two 16B slots per half-tile
    const int o_0 = t * 16, o_1 = t * 16 + 8192;
    const int rl0 = o_0 >> 7, rl1 = o_1 >> 7;
    const int ss0 = ((o_0 >> 4) & 7) ^ (rl0 & 7);
    const int ss1 = ((o_1 >> 4) & 7) ^ (rl1 & 7);

    const __hip_bfloat16* pa[2][2];
    const __hip_bfloat16* pb[2][2];
#pragma unroll
    for (int hf = 0; hf < 2; ++hf) {
        pa[hf][0] = Pn + (size_t)(brow + hf * 128 + rl0) * D + ss0 * 8;
        pa[hf][1] = Pn + (size_t)(brow + hf * 128 + rl1) * D + ss1 * 8;
        pb[hf][0] = An + (size_t)(bcol + hf * 128 + rl0) * D + ss0 * 8;
        pb[hf][1] = An + (size_t)(bcol + hf * 128 + rl1) * D + ss1 * 8;
    }

    auto stage = [&](int dn) {
        unsigned char* lA = lds + dn * 32768;
        unsigned char* lB = lds + 65536 + dn * 32768;
#pragma unroll
        for (int hf = 0; hf < 2; ++hf) {
            __builtin_amdgcn_global_load_lds((gvoid*)pa[hf][0], (lvoid*)(lA + hf * 16384 + o_0), 16, 0, 0);
            __builtin_amdgcn_global_load_lds((gvoid*)pa[hf][1], (lvoid*)(lA + hf * 16384 + o_1), 16, 0, 0);
            __builtin_amdgcn_global_load_lds((gvoid*)pb[hf][0], (lvoid*)(lB + hf * 16384 + o_0), 16, 0, 0);
            __builtin_amdgcn_global_load_lds((gvoid*)pb[hf][1], (lvoid*)(lB + hf * 16384 + o_1), 16, 0, 0);
            pa[hf][0] += 64; pa[hf][1] += 64;
            pb[hf][0] += 64; pb[hf][1] += 64;
        }
    };

    f32x4 acc[8][4];
#pragma unroll
    for (int mi = 0; mi < 8; ++mi)
#pragma unroll
        for (int ni = 0; ni < 4; ++ni)
#pragma unroll
            for (int j = 0; j < 4; ++j) acc[mi][ni][j] = 0.0f;

    // prologue: stage tile 0, wait, barrier
    stage(0);
    asm volatile("s_waitcnt vmcnt(0)" ::: "memory");
    __builtin_amdgcn_s_barrier();

    short8 a[2][4], b0[2][2], b1[2][2];

    for (int tn = 0; tn < NT; ++tn) {
        const int c = tn & 1;
        const unsigned char* lAc = lds + c * 32768 + wm * 16384 + l15 * 128;
        const unsigned char* lBc = lds + 65536 + c * 32768 + (wn >> 1) * 16384 + ((wn & 1) * 64 + l15) * 128;

        // ---- P0: read a(qr0), b0(qc0); stage next tile; MFMA quad (0,0) ----
#pragma unroll
        for (int mi = 0; mi < 4; ++mi) {
            a[0][mi] = *(const short8*)(lAc + mi * 2048 + (kb0 ^ swz));
            a[1][mi] = *(const short8*)(lAc + mi * 2048 + (kb1 ^ swz));
        }
#pragma unroll
        for (int nf = 0; nf < 2; ++nf) {
            b0[0][nf] = *(const short8*)(lBc + nf * 2048 + (kb0 ^ swz));
            b0[1][nf] = *(const short8*)(lBc + nf * 2048 + (kb1 ^ swz));
        }
        if (tn < NT - 1) stage(c ^ 1);
        __builtin_amdgcn_s_barrier();
        __builtin_amdgcn_s_setprio(1);
#pragma unroll
        for (int ks = 0; ks < 2; ++ks)
#pragma unroll
            for (int mi = 0; mi < 4; ++mi)
#pragma unroll
                for (int nf = 0; nf < 2; ++nf)
                    acc[mi][nf] = __builtin_amdgcn_mfma_f32_16x16x32_bf16(a[ks][mi], b0[ks][nf], acc[mi][nf], 0, 0, 0);
        __builtin_amdgcn_s_setprio(0);
        __builtin_amdgcn_s_barrier();

        // ---- P1: read b1(qc1); MFMA quad (0,1) ----
#pragma unroll
        for (int nf = 0; nf < 2; ++nf) {
            b1[0][nf] = *(const short8*)(lBc + 4096 + nf * 2048 + (kb0 ^ swz));
            b1[1][nf] = *(const short8*)(lBc + 4096 + nf * 2048 + (kb1 ^ swz));
        }
        __builtin_amdgcn_s_barrier();
        __builtin_amdgcn_s_setprio(1);
#pragma unroll
        for (int ks = 0; ks < 2; ++ks)
#pragma unroll
            for (int mi = 0; mi < 4; ++mi)
#pragma unroll
                for (int nf = 0; nf < 2; ++nf)
                    acc[mi][2 + nf] = __builtin_amdgcn_mfma_f32_16x16x32_bf16(a[ks][mi], b1[ks][nf], acc[mi][2 + nf], 0, 0, 0);
        __builtin_amdgcn_s_setprio(0);
        __builtin_amdgcn_s_barrier();

        // ---- P2: read a(qr1); MFMA quad (1,1) ----
#pragma unroll
        for (int mi = 0; mi < 4; ++mi) {
            a[0][mi] = *(const short8*)(lAc + 8192 + mi * 2048 + (kb0 ^ swz));
            a[1][mi] = *(const short8*)(lAc + 8192 + mi * 2048 + (kb1 ^ swz));
        }
        __builtin_amdgcn_s_barrier();
        __builtin_amdgcn_s_setprio(1);
#pragma unroll
        for (int ks = 0; ks < 2; ++ks)
#pragma unroll
            for (int mi = 0; mi < 4; ++mi)
#pragma unroll
                for (int nf = 0; nf < 2; ++nf)
                    acc[4 + mi][2 + nf] = __builtin_amdgcn_mfma_f32_16x16x32_bf16(a[ks][mi], b1[ks][nf], acc[4 + mi][2 + nf], 0, 0, 0);
        __builtin_amdgcn_s_setprio(0);
        __builtin_amdgcn_s_barrier();

        // ---- P3: no reads; MFMA quad (1,0); tile-end wait ----
        __builtin_amdgcn_s_setprio(1);
#pragma unroll
        for (int ks = 0; ks < 2; ++ks)
#pragma unroll
            for (int mi = 0; mi < 4; ++mi)
#pragma unroll
                for (int nf = 0; nf < 2; ++nf)
                    acc[4 + mi][nf] = __builtin_amdgcn_mfma_f32_16x16x32_bf16(a[ks][mi], b0[ks][nf], acc[4 + mi][nf], 0, 0, 0);
        __builtin_amdgcn_s_setprio(0);
        asm volatile("s_waitcnt vmcnt(0) lgkmcnt(0)" ::: "memory");
        __builtin_amdgcn_s_barrier();
    }

    // ---- epilogue: exp + row-sum over the wave's 64 cols + one atomic per row ----
#pragma unroll
    for (int mi = 0; mi < 8; ++mi) {
#pragma unroll
        for (int j = 0; j < 4; ++j) {
            float v = 0.0f;
#pragma unroll
            for (int ni = 0; ni < 4; ++ni)
                v += __expf(acc[mi][ni][j] * wv - s);
            v += __shfl_xor(v, 1);
            v += __shfl_xor(v, 2);
            v += __shfl_xor(v, 4);
            v += __shfl_xor(v, 8);
            if (l15 == 0) {
                int row = brow + wm * 128 + mi * 16 + lhi * 4 + j;
                atomicAdd(&sumexp[row], v);
            }
        }
    }
}

// Fallback (uncached ws): round-1 proven kernel, normalizes on the fly.
__global__ __launch_bounds__(256, 2) void gemm_lse_small(
    const float* __restrict__ x,
    const float* __restrict__ pinv, const float* __restrict__ ainv,
    const float* __restrict__ wp, float* __restrict__ sumexp, int N)
{
    __shared__ __align__(16) unsigned char lds[81920];
    unsigned char* As = lds;
    unsigned char* Bs = lds + 65536;

    const int t = threadIdx.x;
    const int rb = blockIdx.y, cs = blockIdx.x;
    const int lane = t & 63, w = t >> 6;
    const int wr = w >> 1, wc = w & 1;
    const int l15 = lane & 15, lhi = lane >> 4;

    const int colsPer = N >> 3;
    const int CT = colsPer / 64;
    const int Q = CT * (D / 64);

    {
        int r = t >> 2;
        int kq = (t & 3) << 7;
        int grow = rb * 64 + r;
        const float4* src = (const float4*)(x + (size_t)(2 * grow + 1) * D);
        float sc = pinv[grow];
#pragma unroll
        for (int i2 = 0; i2 < 16; ++i2) {
            int k0 = kq + i2 * 8;
            float4 v0 = src[k0 >> 2], v1 = src[(k0 >> 2) + 1];
            *(int4*)(As + r * 1024 + ((k0 * 2) ^ ((r & 7) << 4))) = pack8f(v0, v1, sc);
        }
    }

    const int cl = t >> 2;
    const int kq = (t & 3) << 4;

    auto loadB = [&](int q, int4& oa, int4& ob) {
        int ct = q >> 3, kc = q & 7;
        int c = cs * colsPer + ct * 64 + cl;
        int k = kc * 64 + kq;
        const float4* src = (const float4*)(x + (size_t)(2 * c) * D + k);
        float sc = ainv[c];
        float4 v0 = src[0], v1 = src[1], v2 = src[2], v3 = src[3];
        oa = pack8f(v0, v1, sc);
        ob = pack8f(v2, v3, sc);
    };
    auto writeB = [&](int buf, const int4& oa, const int4& ob) {
        unsigned char* bb = Bs + buf * 8192 + cl * 128;
        int kb0 = kq * 2;
        *(int4*)(bb + (kb0 ^ ((cl & 7) << 4))) = oa;
        *(int4*)(bb + ((kb0 + 16) ^ ((cl & 7) << 4))) = ob;
    };

    const float wv = *wp;
    const float s = fabsf(wv);

    int4 ba, bb2;
    loadB(0, ba, bb2);
    __syncthreads();
    writeB(0, ba, bb2);
    __syncthreads();

    f32x4 acc[2][2];
    float rs[2][4];
#pragma unroll
    for (int mi = 0; mi < 2; ++mi) {
#pragma unroll
        for (int j = 0; j < 4; ++j) rs[mi][j] = 0.0f;
#pragma unroll
        for (int ni = 0; ni < 2; ++ni)
#pragma unroll
            for (int j = 0; j < 4; ++j) acc[mi][ni][j] = 0.0f;
    }

    for (int q = 0; q < Q; ++q) {
        const int kc = q & 7;
        const bool more = (q + 1 < Q);
        if (more) loadB(q + 1, ba, bb2);
        const unsigned char* Bp = Bs + (q & 1) * 8192;
#pragma unroll
        for (int ks = 0; ks < 2; ++ks) {
            int ka = kc * 64 + ks * 32 + lhi * 8;
            int ra0 = wr * 32 + l15, ra1 = ra0 + 16;
            short8 a0 = *(const short8*)(As + ra0 * 1024 + ((ka * 2) ^ ((ra0 & 7) << 4)));
            short8 a1 = *(const short8*)(As + ra1 * 1024 + ((ka * 2) ^ ((ra1 & 7) << 4)));
            int kb = ks * 32 + lhi * 8;
            int c0 = wc * 32 + l15, c1 = c0 + 16;
            short8 b0 = *(const short8*)(Bp + c0 * 128 + ((kb * 2) ^ ((c0 & 7) << 4)));
            short8 b1 = *(const short8*)(Bp + c1 * 128 + ((kb * 2) ^ ((c1 & 7) << 4)));
            acc[0][0] = __builtin_amdgcn_mfma_f32_16x16x32_bf16(a0, b0, acc[0][0], 0, 0, 0);
            acc[0][1] = __builtin_amdgcn_mfma_f32_16x16x32_bf16(a0, b1, acc[0][1], 0, 0, 0);
            acc[1][0] = __builtin_amdgcn_mfma_f32_16x16x32_bf16(a1, b0, acc[1][0], 0, 0, 0);
            acc[1][1] = __builtin_amdgcn_mfma_f32_16x16x32_bf16(a1, b1, acc[1][1], 0, 0, 0);
        }
        if (kc == 7) {
#pragma unroll
            for (int mi = 0; mi < 2; ++mi)
#pragma unroll
                for (int ni = 0; ni < 2; ++ni)
#pragma unroll
                    for (int j = 0; j < 4; ++j) {
                        rs[mi][j] += __expf(acc[mi][ni][j] * wv - s);
                        acc[mi][ni][j] = 0.0f;
                    }
        }
        if (more) {
            __syncthreads();
            writeB((q + 1) & 1, ba, bb2);
            __syncthreads();
        }
    }

#pragma unroll
    for (int mi = 0; mi < 2; ++mi)
#pragma unroll
        for (int j = 0; j < 4; ++j) {
            float v = rs[mi][j];
            v += __shfl_xor(v, 1);
            v += __shfl_xor(v, 2);
            v += __shfl_xor(v, 4);
            v += __shfl_xor(v, 8);
            if (l15 == 0) {
                int row = rb * 64 + wr * 32 + mi * 16 + lhi * 4 + j;
                atomicAdd(&sumexp[row], v);
            }
        }
}

// Fallback norm (writes pinv/ainv too)
__global__ __launch_bounds__(512) void norm_small(
    const float* __restrict__ x,
    float* __restrict__ pinv, float* __restrict__ ainv,
    float* __restrict__ diag, float* __restrict__ sumexp)
{
    const int t = threadIdx.x;
    const int i = blockIdx.x * 8 + (t >> 6);
    const int lane = t & 63;
    const float4* ap = (const float4*)(x + (size_t)(2 * i) * D);
    const float4* pp = (const float4*)(x + (size_t)(2 * i + 1) * D);
    float4 a0 = ap[lane * 2], a1 = ap[lane * 2 + 1];
    float4 p0 = pp[lane * 2], p1 = pp[lane * 2 + 1];
    float ssa = a0.x*a0.x + a0.y*a0.y + a0.z*a0.z + a0.w*a0.w
              + a1.x*a1.x + a1.y*a1.y + a1.z*a1.z + a1.w*a1.w;
    float ssp = p0.x*p0.x + p0.y*p0.y + p0.z*p0.z + p0.w*p0.w
              + p1.x*p1.x + p1.y*p1.y + p1.z*p1.z + p1.w*p1.w;
    float dt  = p0.x*a0.x + p0.y*a0.y + p0.z*a0.z + p0.w*a0.w
              + p1.x*a1.x + p1.y*a1.y + p1.z*a1.z + p1.w*a1.w;
#pragma unroll
    for (int m = 1; m < 64; m <<= 1) {
        ssa += __shfl_xor(ssa, m);
        ssp += __shfl_xor(ssp, m);
        dt  += __shfl_xor(dt, m);
    }
    float an = sqrtf(ssa), pn = sqrtf(ssp);
    if (lane == 0) {
        ainv[i] = 1.0f / fmaxf(an, 1e-30f);
        pinv[i] = 1.0f / fmaxf(pn, 1e-30f);
        diag[i] = dt / fmaxf(pn * an, 1e-8f);
        sumexp[i] = 0.0f;
    }
}

// Kernel 3: loss_i = |w| + log(sumexp_i) - w*diag_i ; out = mean(loss)
__global__ __launch_bounds__(1024) void finalize_kernel(
    const float* __restrict__ sumexp, const float* __restrict__ diag,
    const float* __restrict__ wp, float* __restrict__ out, int N)
{
    const int t = threadIdx.x;
    const float w = *wp;
    const float s = fabsf(w);
    float acc = 0.0f;
    for (int i = t; i < N; i += 1024)
        acc += s + logf(sumexp[i]) - w * diag[i];
#pragma unroll
    for (int m = 1; m < 64; m <<= 1) acc += __shfl_xor(acc, m);
    __shared__ float red[16];
    if ((t & 63) == 0) red[t >> 6] = acc;
    __syncthreads();
    if (t == 0) {
        float v = 0.0f;
#pragma unroll
        for (int i = 0; i < 16; ++i) v += red[i];
        out[0] = v / (float)N;
    }
}

extern "C" void kernel_launch(void* const* d_in, const int* in_sizes, int n_in,
                              void* d_out, int out_size, void* d_ws, size_t ws_size,
                              hipStream_t stream) {
    const float* x  = (const float*)d_in[0];
    const float* wp = (const float*)d_in[1];
    // b (d_in[2]) cancels in log_softmax diagonal term.

    const int N = in_sizes[0] / (2 * D);     // 8192

    char* ws = (char*)d_ws;
    size_t nf = (size_t)N * 4;
    float* pinv   = (float*)(ws);
    float* ainv   = (float*)(ws + nf);
    float* diag   = (float*)(ws + 2 * nf);
    float* sumexp = (float*)(ws + 3 * nf);
    size_t base = (4 * nf + 255) & ~(size_t)255;
    __hip_bfloat16* Pn = (__hip_bfloat16*)(ws + base);
    __hip_bfloat16* An = (__hip_bfloat16*)(ws + base + (size_t)N * D * 2);
    const bool cached = ws_size >= base + (size_t)N * D * 4;

    if (cached) {
        norm_kernel<<<N / 8, 512, 0, stream>>>(x, diag, sumexp, Pn, An);
        const int nbx = N / 256;             // 32
        gemm_lse_256<<<nbx * nbx, 512, 0, stream>>>(Pn, An, wp, sumexp, nbx);
    } else {
        norm_small<<<N / 8, 512, 0, stream>>>(x, pinv, ainv, diag, sumexp);
        dim3 grid(8, N / 64);
        gemm_lse_small<<<grid, 256, 0, stream>>>(x, pinv, ainv, wp, sumexp, N);
    }

    finalize_kernel<<<1, 1024, 0, stream>>>(sumexp, diag, wp, (float*)d_out, N);
}